// Round 2
// baseline (103.405 us; speedup 1.0000x reference)
//
#include <hip/hip_runtime.h>
#include <hip/hip_bf16.h>
#include <stdint.h>

#define BB 64
#define TT 4096
#define NS 32
#define DD 64
#define CH 64      // chunks per subject
#define CL 64      // chunk length
#define WU 24      // warmup steps (mixing: contraction ~0.15/step -> ~1e-20)
#define LOG2PI 1.8378770664093453f
#define LN2F 0.6931471805599453f

typedef float f2 __attribute__((ext_vector_type(2)));

__device__ __forceinline__ f2 pk_fma(f2 a, f2 b, f2 c) {
  f2 d;
  asm("v_pk_fma_f32 %0, %1, %2, %3" : "=v"(d) : "v"(a), "v"(b), "v"(c));
  return d;
}

__device__ __forceinline__ uint32_t cvt_pk_bf16(float lo, float hi) {
  uint32_t d;
  asm("v_cvt_pk_bf16_f32 %0, %1, %2" : "=v"(d) : "v"(lo), "v"(hi));
  return d;
}

// sum over each 32-lane half; result valid in lanes 31 and 63
__device__ __forceinline__ float dpp_sum32(float v) {
  float r = v; int x;
  x = __builtin_amdgcn_update_dpp(0, __float_as_int(r), 0x111, 0xF, 0xF, true); r += __int_as_float(x);
  x = __builtin_amdgcn_update_dpp(0, __float_as_int(r), 0x112, 0xF, 0xF, true); r += __int_as_float(x);
  x = __builtin_amdgcn_update_dpp(0, __float_as_int(r), 0x114, 0xF, 0xF, true); r += __int_as_float(x);
  x = __builtin_amdgcn_update_dpp(0, __float_as_int(r), 0x118, 0xF, 0xF, true); r += __int_as_float(x);
  x = __builtin_amdgcn_update_dpp(0, __float_as_int(r), 0x142, 0xF, 0xF, true); r += __int_as_float(x);
  return r;
}

// max over all 64 lanes; result valid in lane 63
__device__ __forceinline__ float dpp_max64(float v) {
  float r = v; int x;
  x = __builtin_amdgcn_update_dpp(__float_as_int(r), __float_as_int(r), 0x111, 0xF, 0xF, false); r = fmaxf(r, __int_as_float(x));
  x = __builtin_amdgcn_update_dpp(__float_as_int(r), __float_as_int(r), 0x112, 0xF, 0xF, false); r = fmaxf(r, __int_as_float(x));
  x = __builtin_amdgcn_update_dpp(__float_as_int(r), __float_as_int(r), 0x114, 0xF, 0xF, false); r = fmaxf(r, __int_as_float(x));
  x = __builtin_amdgcn_update_dpp(__float_as_int(r), __float_as_int(r), 0x118, 0xF, 0xF, false); r = fmaxf(r, __int_as_float(x));
  x = __builtin_amdgcn_update_dpp(__float_as_int(r), __float_as_int(r), 0x142, 0xF, 0xF, false); r = fmaxf(r, __int_as_float(x));
  x = __builtin_amdgcn_update_dpp(__float_as_int(r), __float_as_int(r), 0x143, 0xF, 0xF, false); r = fmaxf(r, __int_as_float(x));
  return r;
}

// ---------------- K1: preprocess A (softmax rows), pi, U/V (transposed [d][n]), bias
__global__ void k_pre(const float* __restrict__ tm, const float* __restrict__ sp,
                      const float* __restrict__ mus, const float* __restrict__ lv,
                      float* __restrict__ Amat, float* __restrict__ pivec,
                      float* __restrict__ UT, float* __restrict__ VT,
                      float* __restrict__ bias)
{
  const int tid = threadIdx.x;
  if (tid < 32) {
    float m = -1e30f;
    for (int jj = 0; jj < 32; ++jj) m = fmaxf(m, tm[tid*32+jj]);
    float s = 0.f;
    for (int jj = 0; jj < 32; ++jj) s += expf(tm[tid*32+jj] - m);
    float inv = 1.0f / s;
    for (int jj = 0; jj < 32; ++jj) Amat[tid*32+jj] = expf(tm[tid*32+jj] - m) * inv;
  }
  if (tid == 32) {
    float m = -1e30f;
    for (int jj = 0; jj < 32; ++jj) m = fmaxf(m, sp[jj]);
    float s = 0.f;
    for (int jj = 0; jj < 32; ++jj) s += expf(sp[jj] - m);
    float inv = 1.0f / s;
    for (int jj = 0; jj < 32; ++jj) pivec[jj] = expf(sp[jj] - m) * inv;
  }
  for (int i = tid; i < NS*DD; i += 256) {
    int n = i >> 6, d = i & 63;
    float iv = expf(-lv[i]);
    UT[d*NS + n] = -0.5f * iv;
    VT[d*NS + n] = mus[i] * iv;
  }
  if (tid < 32) {
    float s2 = 0.f, slv = 0.f;
    for (int d = 0; d < DD; ++d) {
      float m_ = mus[tid*DD + d], l_ = lv[tid*DD + d];
      s2 = fmaf(m_*m_, expf(-l_), s2);
      slv += l_;
    }
    bias[tid] = -0.5f * (s2 + slv + (float)DD * LOG2PI);
  }
}

// ---------------- K2: emission -> blin (bf16, shifted by per-chunk max Kc)
// Xs-only LDS (17.4 KB) -> ~9 blocks/CU; U/V rows come from L1 (one 128B line
// per row, broadcast across the wave).
__global__ __launch_bounds__(128, 4) void k_emis(
    const float* __restrict__ Xg,
    const float* __restrict__ UT,
    const float* __restrict__ VT,
    const float* __restrict__ bias,
    uint32_t* __restrict__ blin32,
    float* __restrict__ Kc)
{
  __shared__ __align__(16) float Xs[64][68];   // 68 -> 272B rows: 16B-aligned float4 reads
  __shared__ float smax[2];
  const int tid = threadIdx.x;
  const int blk = blockIdx.x;
  const int b = blk >> 6;
  const int c = blk & 63;
  const int t0 = c << 6;

  {
    const float* src = Xg + (size_t)(b*TT + t0) * DD;
    for (int i = tid; i < 64*64; i += 128) Xs[i >> 6][i & 63] = src[i];
  }
  __syncthreads();

  const int tq = tid >> 3;   // 0..15
  const int nq = tid & 7;    // 0..7

  f2 acc[4][2];
  #pragma unroll
  for (int a = 0; a < 4; ++a) { acc[a][0].x = 0.f; acc[a][0].y = 0.f; acc[a][1].x = 0.f; acc[a][1].y = 0.f; }

  #pragma unroll 2
  for (int d0 = 0; d0 < 64; d0 += 4) {
    float4 xv[4];
    #pragma unroll
    for (int t4 = 0; t4 < 4; ++t4)
      xv[t4] = *(const float4*)&Xs[tq + (t4 << 4)][d0];
    #pragma unroll
    for (int dd = 0; dd < 4; ++dd) {
      const int d = d0 + dd;
      float4 u4 = *(const float4*)&UT[d * NS + (nq << 2)];
      float4 v4 = *(const float4*)&VT[d * NS + (nq << 2)];
      f2 u01 = {u4.x, u4.y};
      f2 u23 = {u4.z, u4.w};
      f2 v01 = {v4.x, v4.y};
      f2 v23 = {v4.z, v4.w};
      #pragma unroll
      for (int t4 = 0; t4 < 4; ++t4) {
        float x = ((const float*)&xv[t4])[dd];
        f2 x2 = {x, x};
        f2 tmp0 = pk_fma(x2, u01, v01);
        f2 tmp1 = pk_fma(x2, u23, v23);
        acc[t4][0] = pk_fma(x2, tmp0, acc[t4][0]);
        acc[t4][1] = pk_fma(x2, tmp1, acc[t4][1]);
      }
    }
  }

  float b4[4];
  #pragma unroll
  for (int k = 0; k < 4; ++k) b4[k] = bias[(nq << 2) + k];

  float lb[4][4];
  float lmax = -1e30f;
  #pragma unroll
  for (int t4 = 0; t4 < 4; ++t4) {
    lb[t4][0] = acc[t4][0].x + b4[0];
    lb[t4][1] = acc[t4][0].y + b4[1];
    lb[t4][2] = acc[t4][1].x + b4[2];
    lb[t4][3] = acc[t4][1].y + b4[3];
    #pragma unroll
    for (int k = 0; k < 4; ++k) lmax = fmaxf(lmax, lb[t4][k]);
  }

  float wm = dpp_max64(lmax);
  if ((tid & 63) == 63) smax[tid >> 6] = wm;
  __syncthreads();
  const float KcV = fmaxf(smax[0], smax[1]);
  if (tid == 0) Kc[(b << 6) + c] = KcV;

  #pragma unroll
  for (int t4 = 0; t4 < 4; ++t4) {
    const int t = t0 + tq + (t4 << 4);
    float e0 = __expf(lb[t4][0] - KcV);
    float e1 = __expf(lb[t4][1] - KcV);
    float e2 = __expf(lb[t4][2] - KcV);
    float e3 = __expf(lb[t4][3] - KcV);
    uint2 w;
    w.x = cvt_pk_bf16(e0, e1);
    w.y = cvt_pk_bf16(e2, e3);
    ((uint2*)blin32)[((size_t)(b*TT + t) << 3) + nq] = w;
  }
}

// ---------------- K3: chunked linear-space scan (2 chunks per wave)
__global__ __launch_bounds__(256, 2) void k_scan(
    const uint32_t* __restrict__ blin32,
    const float* __restrict__ Kc,
    const float* __restrict__ Amat,
    const float* __restrict__ pivec,
    float* __restrict__ out,
    float* __restrict__ Mc)
{
  __shared__ __align__(16) float vbuf[4][64];
  const int tid  = threadIdx.x;
  const int wave = tid >> 6;
  const int lane = tid & 63;
  const int half = lane >> 5;
  const int j    = lane & 31;
  const int wgid = blockIdx.x * 4 + wave;      // 0..2047
  const int g0   = wgid << 1;
  const int b    = g0 >> 6;
  const int c    = (g0 & 63) + half;           // this half's chunk
  const int cs   = c << 6;
  const bool isC0 = (c == 0);

  f2 col2[16];
  #pragma unroll
  for (int i = 0; i < 16; ++i) {
    col2[i].x = Amat[(2*i) * NS + j];
    col2[i].y = Amat[(2*i+1) * NS + j];
  }
  const float pij = pivec[j];
  const float KcH = Kc[(b << 6) + c];
  const int outbase = b * TT + cs;

  int tstart = cs - WU; if (tstart < 0) tstart = 0;  // only chunk 0 clamps
  int idx = (b * TT + tstart) * 16 + (j >> 1);
  const int idxMain = (b * TT + cs) * 16 + (j >> 1);
  const int shamt = (j & 1) ? 0 : 16;

  uint32_t bl[8];
  #pragma unroll
  for (int p = 0; p < 8; ++p) { bl[p] = blin32[idx]; idx += 16; }

  float v = 1.0f, S = 0.0f, sPrev = 1.0f;
  float* vb = &vbuf[wave][0];
  const float4* pv4 = (const float4*)(vb + (half << 5));

  auto STEP = [&](int q, int slot) {
    // consume s_{t-1}: rescale exponent + (in main phase) emit previous output
    int e = ((__float_as_int(sPrev) >> 23) & 0xFF) - 126;
    float rf = __int_as_float((127 - e) << 23);
    if (q >= WU) {
      float outv = __log2f(sPrev) * LN2F + S;
      if (q == WU) {
        if ((lane & 31) == 0) Mc[(b << 6) + c] = outv;
      } else {
        if ((lane & 31) == 0) out[outbase + (q - WU) - 1] = outv;
      }
      S += KcH + (float)e * LN2F;
    } else {
      S += (float)e * LN2F;
    }
    // matvec via LDS broadcast
    vb[lane] = v;
    f2 a0; a0.x = 0.f; a0.y = 0.f;
    f2 a1; a1.x = 0.f; a1.y = 0.f;
    #pragma unroll
    for (int k = 0; k < 8; ++k) {
      float4 p = pv4[k];
      f2 plo; plo.x = p.x; plo.y = p.y;
      f2 phi; phi.x = p.z; phi.y = p.w;
      a0 = pk_fma(plo, col2[2*k],   a0);
      a1 = pk_fma(phi, col2[2*k+1], a1);
    }
    float dot = (a0.x + a0.y) + (a1.x + a1.y);
    if (q == WU) dot = isC0 ? v : dot;          // chunk 0: alpha0 = pi (no transition)
    if (q == WU - 8) idx = idxMain;             // prefetch stream jumps to main phase
    uint32_t raw = bl[slot];
    bl[slot] = blin32[idx]; idx += 16;          // prefetch step q+8
    float blf = __int_as_float((raw << shamt) & 0xFFFF0000u);
    v = dot * blf * rf;
    if (q == WU - 1) { if (isC0) { v = pij; S = 0.0f; } }  // reset chunk 0 before main
    float r = dpp_sum32(v);
    sPrev = __int_as_float(__builtin_amdgcn_ds_swizzle(__float_as_int(r), 0x3E0));
  };

  #pragma unroll 1
  for (int m = 0; m < (WU + CL) / 8; ++m) {
    const int q0 = m << 3;
    STEP(q0 + 0, 0); STEP(q0 + 1, 1); STEP(q0 + 2, 2); STEP(q0 + 3, 3);
    STEP(q0 + 4, 4); STEP(q0 + 5, 5); STEP(q0 + 6, 6); STEP(q0 + 7, 7);
  }
  {
    float outv = __log2f(sPrev) * LN2F + S;
    if ((lane & 31) == 0) out[outbase + CL - 1] = outv;
  }
}

// ---------------- K4a: per-subject prefix of chunk offsets
__global__ void k_stitch(const float* __restrict__ out, const float* __restrict__ Mcc,
                         float* __restrict__ Delta)
{
  const int b = blockIdx.x;
  const int c = threadIdx.x;     // 64 threads
  float term = 0.0f;
  if (c > 0) term = out[b * TT + (c << 6) - 1] - Mcc[(b << 6) + c];
  for (int off = 1; off < 64; off <<= 1) {
    float up = __shfl_up(term, off);
    if (c >= off) term += up;
  }
  Delta[(b << 6) + c] = term;
}

// ---------------- K4b: add offsets
__global__ void k_add(float* __restrict__ out, const float* __restrict__ Delta)
{
  const int i = blockIdx.x * 256 + threadIdx.x;   // i < B*T
  const int b = i >> 12;
  const int t = i & 4095;
  out[i] += Delta[(b << 6) + (t >> 6)];
}

extern "C" void kernel_launch(void* const* d_in, const int* in_sizes, int n_in,
                              void* d_out, int out_size, void* d_ws, size_t ws_size,
                              hipStream_t stream) {
  const float* X   = (const float*)d_in[0];
  const float* tm  = (const float*)d_in[1];
  const float* sp  = (const float*)d_in[2];
  const float* mus = (const float*)d_in[3];
  const float* lv  = (const float*)d_in[4];
  float* out = (float*)d_out;

  char* ws = (char*)d_ws;
  size_t off = 0;
  uint32_t* blin32 = (uint32_t*)(ws + off); off += (size_t)BB * TT * NS * 2 + 4096;
  float* Kcv   = (float*)(ws + off); off += (size_t)BB * CH * 4;
  float* Mcc   = (float*)(ws + off); off += (size_t)BB * CH * 4;
  float* Delta = (float*)(ws + off); off += (size_t)BB * CH * 4;
  float* Amat  = (float*)(ws + off); off += (size_t)NS * NS * 4;
  float* pivec = (float*)(ws + off); off += 256;
  float* UT    = (float*)(ws + off); off += (size_t)NS * DD * 4;
  float* VT    = (float*)(ws + off); off += (size_t)NS * DD * 4;
  float* bias  = (float*)(ws + off); off += 256;

  k_pre<<<dim3(1), dim3(256), 0, stream>>>(tm, sp, mus, lv, Amat, pivec, UT, VT, bias);
  k_emis<<<dim3(BB * CH), dim3(128), 0, stream>>>(X, UT, VT, bias, blin32, Kcv);
  k_scan<<<dim3(512), dim3(256), 0, stream>>>(blin32, Kcv, Amat, pivec, out, Mcc);
  k_stitch<<<dim3(BB), dim3(64), 0, stream>>>(out, Mcc, Delta);
  k_add<<<dim3((BB * TT) / 256), dim3(256), 0, stream>>>(out, Delta);
}

// Round 4
// 85.623 us; speedup vs baseline: 1.2077x; 1.2077x over previous
//
#include <hip/hip_runtime.h>
#include <hip/hip_bf16.h>
#include <stdint.h>

#define BB 64
#define TT 4096
#define NS 32
#define DD 64
#define CH 64      // chunks per subject
#define CL 64      // chunk length
#define WU 24      // warmup steps (mixing: contraction ~0.15/step -> ~1e-20)
#define LOG2PI 1.8378770664093453f
#define LN2F 0.6931471805599453f
#define FLT_MIN_NORM 1.175494350822288e-38f

typedef float f2 __attribute__((ext_vector_type(2)));

__device__ __forceinline__ f2 pk_fma(f2 a, f2 b, f2 c) {
  f2 d;
  asm("v_pk_fma_f32 %0, %1, %2, %3" : "=v"(d) : "v"(a), "v"(b), "v"(c));
  return d;
}

__device__ __forceinline__ uint32_t cvt_pk_bf16(float lo, float hi) {
  uint32_t d;
  asm("v_cvt_pk_bf16_f32 %0, %1, %2" : "=v"(d) : "v"(lo), "v"(hi));
  return d;
}

// sum over each 32-lane half; result valid in lanes 31 and 63
__device__ __forceinline__ float dpp_sum32(float v) {
  float r = v; int x;
  x = __builtin_amdgcn_update_dpp(0, __float_as_int(r), 0x111, 0xF, 0xF, true); r += __int_as_float(x);
  x = __builtin_amdgcn_update_dpp(0, __float_as_int(r), 0x112, 0xF, 0xF, true); r += __int_as_float(x);
  x = __builtin_amdgcn_update_dpp(0, __float_as_int(r), 0x114, 0xF, 0xF, true); r += __int_as_float(x);
  x = __builtin_amdgcn_update_dpp(0, __float_as_int(r), 0x118, 0xF, 0xF, true); r += __int_as_float(x);
  x = __builtin_amdgcn_update_dpp(0, __float_as_int(r), 0x142, 0xF, 0xF, true); r += __int_as_float(x);
  return r;
}

// max over all 64 lanes; result valid in lane 63
__device__ __forceinline__ float dpp_max64(float v) {
  float r = v; int x;
  x = __builtin_amdgcn_update_dpp(__float_as_int(r), __float_as_int(r), 0x111, 0xF, 0xF, false); r = fmaxf(r, __int_as_float(x));
  x = __builtin_amdgcn_update_dpp(__float_as_int(r), __float_as_int(r), 0x112, 0xF, 0xF, false); r = fmaxf(r, __int_as_float(x));
  x = __builtin_amdgcn_update_dpp(__float_as_int(r), __float_as_int(r), 0x114, 0xF, 0xF, false); r = fmaxf(r, __int_as_float(x));
  x = __builtin_amdgcn_update_dpp(__float_as_int(r), __float_as_int(r), 0x118, 0xF, 0xF, false); r = fmaxf(r, __int_as_float(x));
  x = __builtin_amdgcn_update_dpp(__float_as_int(r), __float_as_int(r), 0x142, 0xF, 0xF, false); r = fmaxf(r, __int_as_float(x));
  x = __builtin_amdgcn_update_dpp(__float_as_int(r), __float_as_int(r), 0x143, 0xF, 0xF, false); r = fmaxf(r, __int_as_float(x));
  return r;
}

// ---------------- K1: preprocess A (softmax rows), pi, U/V (transposed [d][n]), bias
__global__ void k_pre(const float* __restrict__ tm, const float* __restrict__ sp,
                      const float* __restrict__ mus, const float* __restrict__ lv,
                      float* __restrict__ Amat, float* __restrict__ pivec,
                      float* __restrict__ UT, float* __restrict__ VT,
                      float* __restrict__ bias)
{
  const int tid = threadIdx.x;
  if (tid < 32) {
    float m = -1e30f;
    for (int jj = 0; jj < 32; ++jj) m = fmaxf(m, tm[tid*32+jj]);
    float s = 0.f;
    for (int jj = 0; jj < 32; ++jj) s += expf(tm[tid*32+jj] - m);
    float inv = 1.0f / s;
    for (int jj = 0; jj < 32; ++jj) Amat[tid*32+jj] = expf(tm[tid*32+jj] - m) * inv;
  }
  if (tid == 32) {
    float m = -1e30f;
    for (int jj = 0; jj < 32; ++jj) m = fmaxf(m, sp[jj]);
    float s = 0.f;
    for (int jj = 0; jj < 32; ++jj) s += expf(sp[jj] - m);
    float inv = 1.0f / s;
    for (int jj = 0; jj < 32; ++jj) pivec[jj] = expf(sp[jj] - m) * inv;
  }
  for (int i = tid; i < NS*DD; i += 256) {
    int n = i >> 6, d = i & 63;
    float iv = expf(-lv[i]);
    UT[d*NS + n] = -0.5f * iv;
    VT[d*NS + n] = mus[i] * iv;
  }
  if (tid < 32) {
    float s2 = 0.f, slv = 0.f;
    for (int d = 0; d < DD; ++d) {
      float m_ = mus[tid*DD + d], l_ = lv[tid*DD + d];
      s2 = fmaf(m_*m_, expf(-l_), s2);
      slv += l_;
    }
    bias[tid] = -0.5f * (s2 + slv + (float)DD * LOG2PI);
  }
}

// ---------------- K2: emission -> blin (bf16, shifted by per-chunk max Kc)
// 256 threads cover 128 t (2 chunks); 4 t-rows per thread (R1-proven scale).
// U/V in LDS (16 KB, broadcast ds_read_b128); X from global: each 16B of X
// is loaded by exactly one wave-instruction once (compulsory traffic only).
__global__ __launch_bounds__(256, 4) void k_emis(
    const float* __restrict__ Xg,
    const float* __restrict__ UT,
    const float* __restrict__ VT,
    const float* __restrict__ bias,
    uint32_t* __restrict__ blin32,
    float* __restrict__ Kc)
{
  __shared__ __align__(16) float Us[64][32];
  __shared__ __align__(16) float Vs[64][32];
  __shared__ float smax[4][2];                 // [wave][chunk-half]
  const int tid = threadIdx.x;
  const int blk = blockIdx.x;                  // 0..2047
  const int b  = blk >> 5;
  const int cc = blk & 31;                     // chunk-pair index
  const int t0 = cc << 7;                      // 128 t per block

  for (int i = tid; i < 64*32; i += 256) {
    Us[i >> 5][i & 31] = UT[i];
    Vs[i >> 5][i & 31] = VT[i];
  }
  __syncthreads();

  const int tq = tid >> 3;   // 0..31
  const int nq = tid & 7;    // 0..7
  const float* xbase = Xg + (size_t)(b*TT + t0) * DD;

  f2 acc[4][2];
  #pragma unroll
  for (int a = 0; a < 4; ++a) {
    acc[a][0].x = 0.f; acc[a][0].y = 0.f;
    acc[a][1].x = 0.f; acc[a][1].y = 0.f;
  }

  #pragma unroll 2
  for (int d0 = 0; d0 < 64; d0 += 4) {
    float4 xv[4];
    #pragma unroll
    for (int t4 = 0; t4 < 4; ++t4)
      xv[t4] = *(const float4*)&xbase[(size_t)(tq + (t4 << 5)) * DD + d0];
    #pragma unroll
    for (int dd = 0; dd < 4; ++dd) {
      const int d = d0 + dd;
      float4 u4 = *(const float4*)&Us[d][nq << 2];
      float4 v4 = *(const float4*)&Vs[d][nq << 2];
      f2 u01; u01.x = u4.x; u01.y = u4.y;
      f2 u23; u23.x = u4.z; u23.y = u4.w;
      f2 v01; v01.x = v4.x; v01.y = v4.y;
      f2 v23; v23.x = v4.z; v23.y = v4.w;
      #pragma unroll
      for (int t4 = 0; t4 < 4; ++t4) {
        float x = ((const float*)&xv[t4])[dd];
        f2 x2; x2.x = x; x2.y = x;
        f2 tmp0 = pk_fma(x2, u01, v01);
        f2 tmp1 = pk_fma(x2, u23, v23);
        acc[t4][0] = pk_fma(x2, tmp0, acc[t4][0]);
        acc[t4][1] = pk_fma(x2, tmp1, acc[t4][1]);
      }
    }
  }

  float b4[4];
  #pragma unroll
  for (int k = 0; k < 4; ++k) b4[k] = bias[(nq << 2) + k];

  float lb[4][4];
  float lmax0 = -1e30f, lmax1 = -1e30f;
  #pragma unroll
  for (int t4 = 0; t4 < 4; ++t4) {
    lb[t4][0] = acc[t4][0].x + b4[0];
    lb[t4][1] = acc[t4][0].y + b4[1];
    lb[t4][2] = acc[t4][1].x + b4[2];
    lb[t4][3] = acc[t4][1].y + b4[3];
    float m = fmaxf(fmaxf(lb[t4][0], lb[t4][1]), fmaxf(lb[t4][2], lb[t4][3]));
    if (t4 < 2) lmax0 = fmaxf(lmax0, m); else lmax1 = fmaxf(lmax1, m);
  }

  float wm0 = dpp_max64(lmax0);
  float wm1 = dpp_max64(lmax1);
  if ((tid & 63) == 63) { smax[tid >> 6][0] = wm0; smax[tid >> 6][1] = wm1; }
  __syncthreads();
  const float K0 = fmaxf(fmaxf(smax[0][0], smax[1][0]), fmaxf(smax[2][0], smax[3][0]));
  const float K1 = fmaxf(fmaxf(smax[0][1], smax[1][1]), fmaxf(smax[2][1], smax[3][1]));
  if (tid == 0) {
    Kc[(b << 6) + (cc << 1)]     = K0;
    Kc[(b << 6) + (cc << 1) + 1] = K1;
  }

  #pragma unroll
  for (int t4 = 0; t4 < 4; ++t4) {
    const int t = t0 + tq + (t4 << 5);
    const float KcV = (t4 < 2) ? K0 : K1;
    float e0 = __expf(lb[t4][0] - KcV);
    float e1 = __expf(lb[t4][1] - KcV);
    float e2 = __expf(lb[t4][2] - KcV);
    float e3 = __expf(lb[t4][3] - KcV);
    uint2 w;
    w.x = cvt_pk_bf16(e0, e1);
    w.y = cvt_pk_bf16(e2, e3);
    ((uint2*)blin32)[((size_t)(b*TT + t) << 3) + nq] = w;
  }
}

// ---------------- K3: chunked linear-space scan (2 chunks per wave)
__global__ __launch_bounds__(256, 2) void k_scan(
    const uint32_t* __restrict__ blin32,
    const float* __restrict__ Kc,
    const float* __restrict__ Amat,
    const float* __restrict__ pivec,
    float* __restrict__ out,
    float* __restrict__ Mc)
{
  __shared__ __align__(16) float vbuf[4][64];
  const int tid  = threadIdx.x;
  const int wave = tid >> 6;
  const int lane = tid & 63;
  const int half = lane >> 5;
  const int j    = lane & 31;
  const int wgid = blockIdx.x * 4 + wave;      // 0..2047
  const int g0   = wgid << 1;
  const int b    = g0 >> 6;
  const int c    = (g0 & 63) + half;           // this half's chunk
  const int cs   = c << 6;
  const bool isC0 = (c == 0);

  f2 col2[16];
  #pragma unroll
  for (int i = 0; i < 16; ++i) {
    col2[i].x = Amat[(2*i) * NS + j];
    col2[i].y = Amat[(2*i+1) * NS + j];
  }
  const float pij = pivec[j];
  const float KcH = Kc[(b << 6) + c];
  const int outbase = b * TT + cs;

  int tstart = cs - WU; if (tstart < 0) tstart = 0;  // only chunk 0 clamps
  int idx = (b * TT + tstart) * 16 + (j >> 1);
  const int idxMain = (b * TT + cs) * 16 + (j >> 1);
  const int shamt = (j & 1) ? 0 : 16;

  uint32_t bl[8];
  #pragma unroll
  for (int p = 0; p < 8; ++p) { bl[p] = blin32[idx]; idx += 16; }

  float v = 1.0f, S = 0.0f, sPrev = 1.0f;
  float* vb = &vbuf[wave][0];
  const float4* pv4 = (const float4*)(vb + (half << 5));

  auto STEP = [&](int q, int slot) {
    // consume s_{t-1}: rescale exponent + (in main phase) emit previous output
    float sP = fmaxf(sPrev, FLT_MIN_NORM);     // NaN-guard: stay normal
    int e = ((__float_as_int(sP) >> 23) & 0xFF) - 126;
    float rf = __int_as_float((127 - e) << 23);
    if (q >= WU) {
      float outv = __log2f(sP) * LN2F + S;
      if (q == WU) {
        if ((lane & 31) == 0) Mc[(b << 6) + c] = outv;
      } else {
        if ((lane & 31) == 0) out[outbase + (q - WU) - 1] = outv;
      }
      S += KcH + (float)e * LN2F;
    } else {
      S += (float)e * LN2F;
    }
    // matvec via LDS broadcast
    vb[lane] = v;
    f2 a0; a0.x = 0.f; a0.y = 0.f;
    f2 a1; a1.x = 0.f; a1.y = 0.f;
    #pragma unroll
    for (int k = 0; k < 8; ++k) {
      float4 p = pv4[k];
      f2 plo; plo.x = p.x; plo.y = p.y;
      f2 phi; phi.x = p.z; phi.y = p.w;
      a0 = pk_fma(plo, col2[2*k],   a0);
      a1 = pk_fma(phi, col2[2*k+1], a1);
    }
    float dot = (a0.x + a0.y) + (a1.x + a1.y);
    if (q == WU) dot = isC0 ? v : dot;          // chunk 0: alpha0 = pi (no transition)
    if (q == WU - 8) idx = idxMain;             // prefetch stream jumps to main phase
    uint32_t raw = bl[slot];
    bl[slot] = blin32[idx]; idx += 16;          // prefetch step q+8
    float blf = __int_as_float((raw << shamt) & 0xFFFF0000u);
    v = dot * blf * rf;
    if (q == WU - 1) { if (isC0) { v = pij; S = 0.0f; } }  // reset chunk 0 before main
    float r = dpp_sum32(v);
    sPrev = __int_as_float(__builtin_amdgcn_ds_swizzle(__float_as_int(r), 0x3E0));
  };

  #pragma unroll 1
  for (int m = 0; m < (WU + CL) / 8; ++m) {
    const int q0 = m << 3;
    STEP(q0 + 0, 0); STEP(q0 + 1, 1); STEP(q0 + 2, 2); STEP(q0 + 3, 3);
    STEP(q0 + 4, 4); STEP(q0 + 5, 5); STEP(q0 + 6, 6); STEP(q0 + 7, 7);
  }
  {
    float sP = fmaxf(sPrev, FLT_MIN_NORM);
    float outv = __log2f(sP) * LN2F + S;
    if ((lane & 31) == 0) out[outbase + CL - 1] = outv;
  }
}

// ---------------- K4a: per-subject prefix of chunk offsets
__global__ void k_stitch(const float* __restrict__ out, const float* __restrict__ Mcc,
                         float* __restrict__ Delta)
{
  const int b = blockIdx.x;
  const int c = threadIdx.x;     // 64 threads
  float term = 0.0f;
  if (c > 0) term = out[b * TT + (c << 6) - 1] - Mcc[(b << 6) + c];
  for (int off = 1; off < 64; off <<= 1) {
    float up = __shfl_up(term, off);
    if (c >= off) term += up;
  }
  Delta[(b << 6) + c] = term;
}

// ---------------- K4b: add offsets
__global__ void k_add(float* __restrict__ out, const float* __restrict__ Delta)
{
  const int i = blockIdx.x * 256 + threadIdx.x;   // i < B*T
  const int b = i >> 12;
  const int t = i & 4095;
  out[i] += Delta[(b << 6) + (t >> 6)];
}

extern "C" void kernel_launch(void* const* d_in, const int* in_sizes, int n_in,
                              void* d_out, int out_size, void* d_ws, size_t ws_size,
                              hipStream_t stream) {
  const float* X   = (const float*)d_in[0];
  const float* tm  = (const float*)d_in[1];
  const float* sp  = (const float*)d_in[2];
  const float* mus = (const float*)d_in[3];
  const float* lv  = (const float*)d_in[4];
  float* out = (float*)d_out;

  char* ws = (char*)d_ws;
  size_t off = 0;
  uint32_t* blin32 = (uint32_t*)(ws + off); off += (size_t)BB * TT * NS * 2 + 4096;
  float* Kcv   = (float*)(ws + off); off += (size_t)BB * CH * 4;
  float* Mcc   = (float*)(ws + off); off += (size_t)BB * CH * 4;
  float* Delta = (float*)(ws + off); off += (size_t)BB * CH * 4;
  float* Amat  = (float*)(ws + off); off += (size_t)NS * NS * 4;
  float* pivec = (float*)(ws + off); off += 256;
  float* UT    = (float*)(ws + off); off += (size_t)NS * DD * 4;
  float* VT    = (float*)(ws + off); off += (size_t)NS * DD * 4;
  float* bias  = (float*)(ws + off); off += 256;

  k_pre<<<dim3(1), dim3(256), 0, stream>>>(tm, sp, mus, lv, Amat, pivec, UT, VT, bias);
  k_emis<<<dim3(BB * CH / 2), dim3(256), 0, stream>>>(X, UT, VT, bias, blin32, Kcv);
  k_scan<<<dim3(512), dim3(256), 0, stream>>>(blin32, Kcv, Amat, pivec, out, Mcc);
  k_stitch<<<dim3(BB), dim3(64), 0, stream>>>(out, Mcc, Delta);
  k_add<<<dim3((BB * TT) / 256), dim3(256), 0, stream>>>(out, Delta);
}

// Round 5
// 75.308 us; speedup vs baseline: 1.3731x; 1.1370x over previous
//
#include <hip/hip_runtime.h>
#include <hip/hip_bf16.h>
#include <stdint.h>

#define BB 64
#define TT 4096
#define NS 32
#define DD 64
#define CH 64      // chunks per subject
#define CL 64      // chunk length
#define WU 24      // warmup steps (mixing: contraction ~0.15/step -> ~1e-20)
#define LOG2PI 1.8378770664093453f
#define LN2F 0.6931471805599453f
#define FLT_MIN_NORM 1.175494350822288e-38f

typedef float f2 __attribute__((ext_vector_type(2)));

__device__ __forceinline__ f2 pk_fma(f2 a, f2 b, f2 c) {
  f2 d;
  asm("v_pk_fma_f32 %0, %1, %2, %3" : "=v"(d) : "v"(a), "v"(b), "v"(c));
  return d;
}

__device__ __forceinline__ uint32_t cvt_pk_bf16(float lo, float hi) {
  uint32_t d;
  asm("v_cvt_pk_bf16_f32 %0, %1, %2" : "=v"(d) : "v"(lo), "v"(hi));
  return d;
}

// sum over each 32-lane half; result valid in lanes 31 and 63
__device__ __forceinline__ float dpp_sum32(float v) {
  float r = v; int x;
  x = __builtin_amdgcn_update_dpp(0, __float_as_int(r), 0x111, 0xF, 0xF, true); r += __int_as_float(x);
  x = __builtin_amdgcn_update_dpp(0, __float_as_int(r), 0x112, 0xF, 0xF, true); r += __int_as_float(x);
  x = __builtin_amdgcn_update_dpp(0, __float_as_int(r), 0x114, 0xF, 0xF, true); r += __int_as_float(x);
  x = __builtin_amdgcn_update_dpp(0, __float_as_int(r), 0x118, 0xF, 0xF, true); r += __int_as_float(x);
  x = __builtin_amdgcn_update_dpp(0, __float_as_int(r), 0x142, 0xF, 0xF, true); r += __int_as_float(x);
  return r;
}

// max over all 64 lanes; result valid in lane 63
__device__ __forceinline__ float dpp_max64(float v) {
  float r = v; int x;
  x = __builtin_amdgcn_update_dpp(__float_as_int(r), __float_as_int(r), 0x111, 0xF, 0xF, false); r = fmaxf(r, __int_as_float(x));
  x = __builtin_amdgcn_update_dpp(__float_as_int(r), __float_as_int(r), 0x112, 0xF, 0xF, false); r = fmaxf(r, __int_as_float(x));
  x = __builtin_amdgcn_update_dpp(__float_as_int(r), __float_as_int(r), 0x114, 0xF, 0xF, false); r = fmaxf(r, __int_as_float(x));
  x = __builtin_amdgcn_update_dpp(__float_as_int(r), __float_as_int(r), 0x118, 0xF, 0xF, false); r = fmaxf(r, __int_as_float(x));
  x = __builtin_amdgcn_update_dpp(__float_as_int(r), __float_as_int(r), 0x142, 0xF, 0xF, false); r = fmaxf(r, __int_as_float(x));
  x = __builtin_amdgcn_update_dpp(__float_as_int(r), __float_as_int(r), 0x143, 0xF, 0xF, false); r = fmaxf(r, __int_as_float(x));
  return r;
}

// ---------------- K1: preprocess (wave-parallel; all loads coalesced)
// 1024 threads, one block. tm: 32 rows x 32 lanes butterfly softmax.
// bias: 32 states x 32 lanes x 2 d. UT/VT: elementwise.
__global__ __launch_bounds__(1024) void k_pre(
    const float* __restrict__ tm, const float* __restrict__ sp,
    const float* __restrict__ mus, const float* __restrict__ lv,
    float* __restrict__ Amat, float* __restrict__ pivec,
    float* __restrict__ UT, float* __restrict__ VT,
    float* __restrict__ bias)
{
  const int tid = threadIdx.x;       // 0..1023
  const int row = tid >> 5;          // 0..31
  const int col = tid & 31;          // 0..31

  // --- transition-matrix row softmax (exp-normalized, matches log_softmax->exp)
  {
    float v = tm[row * 32 + col];
    float m = v;
    #pragma unroll
    for (int mask = 16; mask; mask >>= 1) m = fmaxf(m, __shfl_xor(m, mask));
    float e = __expf(v - m);
    float s = e;
    #pragma unroll
    for (int mask = 16; mask; mask >>= 1) s += __shfl_xor(s, mask);
    Amat[row * 32 + col] = e / s;
  }

  // --- state-prior softmax (lanes 0..31 of wave 0)
  if (tid < 32) {
    float v = sp[tid];
    float m = v;
    #pragma unroll
    for (int mask = 16; mask; mask >>= 1) m = fmaxf(m, __shfl_xor(m, mask));
    float e = __expf(v - m);
    float s = e;
    #pragma unroll
    for (int mask = 16; mask; mask >>= 1) s += __shfl_xor(s, mask);
    pivec[tid] = e / s;
  }

  // --- UT/VT transpose tables
  #pragma unroll
  for (int ii = 0; ii < 2; ++ii) {
    int i = tid + ii * 1024;          // 0..2047
    int n = i >> 6, d = i & 63;
    float iv = __expf(-lv[i]);
    UT[d * NS + n] = -0.5f * iv;
    VT[d * NS + n] = mus[i] * iv;
  }

  // --- bias[n] = -0.5*(sum mu^2*iv + sum lv + D*log2pi)
  {
    float s2 = 0.f, slv = 0.f;
    #pragma unroll
    for (int h = 0; h < 2; ++h) {
      int d = col + h * 32;
      float m_ = mus[row * 64 + d];
      float l_ = lv[row * 64 + d];
      s2 = fmaf(m_ * m_, __expf(-l_), s2);
      slv += l_;
    }
    #pragma unroll
    for (int mask = 16; mask; mask >>= 1) {
      s2  += __shfl_xor(s2, mask);
      slv += __shfl_xor(slv, mask);
    }
    if (col == 0) bias[row] = -0.5f * (s2 + slv + (float)DD * LOG2PI);
  }
}

// ---------------- K2: emission -> blin (bf16, shifted by per-chunk max Kc)
// 256 threads cover 128 t (2 chunks); 4 t-rows per thread. U/V in LDS.
// X double-buffered from global: next d-group's 4 loads issue before current
// group's 64 pk_fma consume (explicit 2-deep pipeline).
__global__ __launch_bounds__(256, 2) void k_emis(
    const float* __restrict__ Xg,
    const float* __restrict__ UT,
    const float* __restrict__ VT,
    const float* __restrict__ bias,
    uint32_t* __restrict__ blin32,
    float* __restrict__ Kc)
{
  __shared__ __align__(16) float Us[64][32];
  __shared__ __align__(16) float Vs[64][32];
  __shared__ float smax[4][2];                 // [wave][chunk-half]
  const int tid = threadIdx.x;
  const int blk = blockIdx.x;                  // 0..2047
  const int b  = blk >> 5;
  const int cc = blk & 31;                     // chunk-pair index
  const int t0 = cc << 7;                      // 128 t per block

  for (int i = tid; i < 64*32; i += 256) {
    Us[i >> 5][i & 31] = UT[i];
    Vs[i >> 5][i & 31] = VT[i];
  }
  __syncthreads();

  const int tq = tid >> 3;   // 0..31
  const int nq = tid & 7;    // 0..7
  const float* xbase = Xg + (size_t)(b*TT + t0) * DD;

  f2 acc[4][2];
  #pragma unroll
  for (int a = 0; a < 4; ++a) {
    acc[a][0].x = 0.f; acc[a][0].y = 0.f;
    acc[a][1].x = 0.f; acc[a][1].y = 0.f;
  }

  float4 xv0[4], xv1[4];
  #pragma unroll
  for (int t4 = 0; t4 < 4; ++t4)
    xv0[t4] = *(const float4*)&xbase[(size_t)(tq + (t4 << 5)) * DD];

  #pragma unroll
  for (int g = 0; g < 16; ++g) {
    const float4* cur = (g & 1) ? xv1 : xv0;
    float4*       nxt = (g & 1) ? xv0 : xv1;
    if (g < 15) {
      #pragma unroll
      for (int t4 = 0; t4 < 4; ++t4)
        nxt[t4] = *(const float4*)&xbase[(size_t)(tq + (t4 << 5)) * DD + (g + 1) * 4];
    }
    #pragma unroll
    for (int dd = 0; dd < 4; ++dd) {
      const int d = (g << 2) + dd;
      float4 u4 = *(const float4*)&Us[d][nq << 2];
      float4 v4 = *(const float4*)&Vs[d][nq << 2];
      f2 u01; u01.x = u4.x; u01.y = u4.y;
      f2 u23; u23.x = u4.z; u23.y = u4.w;
      f2 v01; v01.x = v4.x; v01.y = v4.y;
      f2 v23; v23.x = v4.z; v23.y = v4.w;
      #pragma unroll
      for (int t4 = 0; t4 < 4; ++t4) {
        float x = ((const float*)&cur[t4])[dd];
        f2 x2; x2.x = x; x2.y = x;
        f2 tmp0 = pk_fma(x2, u01, v01);
        f2 tmp1 = pk_fma(x2, u23, v23);
        acc[t4][0] = pk_fma(x2, tmp0, acc[t4][0]);
        acc[t4][1] = pk_fma(x2, tmp1, acc[t4][1]);
      }
    }
  }

  float b4[4];
  #pragma unroll
  for (int k = 0; k < 4; ++k) b4[k] = bias[(nq << 2) + k];

  float lb[4][4];
  float lmax0 = -1e30f, lmax1 = -1e30f;
  #pragma unroll
  for (int t4 = 0; t4 < 4; ++t4) {
    lb[t4][0] = acc[t4][0].x + b4[0];
    lb[t4][1] = acc[t4][0].y + b4[1];
    lb[t4][2] = acc[t4][1].x + b4[2];
    lb[t4][3] = acc[t4][1].y + b4[3];
    float m = fmaxf(fmaxf(lb[t4][0], lb[t4][1]), fmaxf(lb[t4][2], lb[t4][3]));
    if (t4 < 2) lmax0 = fmaxf(lmax0, m); else lmax1 = fmaxf(lmax1, m);
  }

  float wm0 = dpp_max64(lmax0);
  float wm1 = dpp_max64(lmax1);
  if ((tid & 63) == 63) { smax[tid >> 6][0] = wm0; smax[tid >> 6][1] = wm1; }
  __syncthreads();
  const float K0 = fmaxf(fmaxf(smax[0][0], smax[1][0]), fmaxf(smax[2][0], smax[3][0]));
  const float K1 = fmaxf(fmaxf(smax[0][1], smax[1][1]), fmaxf(smax[2][1], smax[3][1]));
  if (tid == 0) {
    Kc[(b << 6) + (cc << 1)]     = K0;
    Kc[(b << 6) + (cc << 1) + 1] = K1;
  }

  #pragma unroll
  for (int t4 = 0; t4 < 4; ++t4) {
    const int t = t0 + tq + (t4 << 5);
    const float KcV = (t4 < 2) ? K0 : K1;
    float e0 = __expf(lb[t4][0] - KcV);
    float e1 = __expf(lb[t4][1] - KcV);
    float e2 = __expf(lb[t4][2] - KcV);
    float e3 = __expf(lb[t4][3] - KcV);
    uint2 w;
    w.x = cvt_pk_bf16(e0, e1);
    w.y = cvt_pk_bf16(e2, e3);
    ((uint2*)blin32)[((size_t)(b*TT + t) << 3) + nq] = w;
  }
}

// ---------------- K3: chunked linear-space scan (2 chunks per wave)
__global__ __launch_bounds__(256, 2) void k_scan(
    const uint32_t* __restrict__ blin32,
    const float* __restrict__ Kc,
    const float* __restrict__ Amat,
    const float* __restrict__ pivec,
    float* __restrict__ out,
    float* __restrict__ Mc)
{
  __shared__ __align__(16) float vbuf[4][64];
  const int tid  = threadIdx.x;
  const int wave = tid >> 6;
  const int lane = tid & 63;
  const int half = lane >> 5;
  const int j    = lane & 31;
  const int wgid = blockIdx.x * 4 + wave;      // 0..2047
  const int g0   = wgid << 1;
  const int b    = g0 >> 6;
  const int c    = (g0 & 63) + half;           // this half's chunk
  const int cs   = c << 6;
  const bool isC0 = (c == 0);

  f2 col2[16];
  #pragma unroll
  for (int i = 0; i < 16; ++i) {
    col2[i].x = Amat[(2*i) * NS + j];
    col2[i].y = Amat[(2*i+1) * NS + j];
  }
  const float pij = pivec[j];
  const float KcH = Kc[(b << 6) + c];
  const int outbase = b * TT + cs;

  int tstart = cs - WU; if (tstart < 0) tstart = 0;  // only chunk 0 clamps
  int idx = (b * TT + tstart) * 16 + (j >> 1);
  const int idxMain = (b * TT + cs) * 16 + (j >> 1);
  const int shamt = (j & 1) ? 0 : 16;

  uint32_t bl[8];
  #pragma unroll
  for (int p = 0; p < 8; ++p) { bl[p] = blin32[idx]; idx += 16; }

  float v = 1.0f, S = 0.0f, sPrev = 1.0f;
  float* vb = &vbuf[wave][0];
  const float4* pv4 = (const float4*)(vb + (half << 5));

  auto STEP = [&](int q, int slot) {
    // consume s_{t-1}: rescale exponent + (in main phase) emit previous output
    float sP = fmaxf(sPrev, FLT_MIN_NORM);     // NaN-guard: stay normal
    int e = ((__float_as_int(sP) >> 23) & 0xFF) - 126;
    float rf = __int_as_float((127 - e) << 23);
    if (q >= WU) {
      float outv = __log2f(sP) * LN2F + S;
      if (q == WU) {
        if ((lane & 31) == 0) Mc[(b << 6) + c] = outv;
      } else {
        if ((lane & 31) == 0) out[outbase + (q - WU) - 1] = outv;
      }
      S += KcH + (float)e * LN2F;
    } else {
      S += (float)e * LN2F;
    }
    // matvec via LDS broadcast
    vb[lane] = v;
    f2 a0; a0.x = 0.f; a0.y = 0.f;
    f2 a1; a1.x = 0.f; a1.y = 0.f;
    #pragma unroll
    for (int k = 0; k < 8; ++k) {
      float4 p = pv4[k];
      f2 plo; plo.x = p.x; plo.y = p.y;
      f2 phi; phi.x = p.z; phi.y = p.w;
      a0 = pk_fma(plo, col2[2*k],   a0);
      a1 = pk_fma(phi, col2[2*k+1], a1);
    }
    float dot = (a0.x + a0.y) + (a1.x + a1.y);
    if (q == WU) dot = isC0 ? v : dot;          // chunk 0: alpha0 = pi (no transition)
    if (q == WU - 8) idx = idxMain;             // prefetch stream jumps to main phase
    uint32_t raw = bl[slot];
    bl[slot] = blin32[idx]; idx += 16;          // prefetch step q+8
    float blf = __int_as_float((raw << shamt) & 0xFFFF0000u);
    v = dot * blf * rf;
    if (q == WU - 1) { if (isC0) { v = pij; S = 0.0f; } }  // reset chunk 0 before main
    float r = dpp_sum32(v);
    sPrev = __int_as_float(__builtin_amdgcn_ds_swizzle(__float_as_int(r), 0x3E0));
  };

  #pragma unroll 1
  for (int m = 0; m < (WU + CL) / 8; ++m) {
    const int q0 = m << 3;
    STEP(q0 + 0, 0); STEP(q0 + 1, 1); STEP(q0 + 2, 2); STEP(q0 + 3, 3);
    STEP(q0 + 4, 4); STEP(q0 + 5, 5); STEP(q0 + 6, 6); STEP(q0 + 7, 7);
  }
  {
    float sP = fmaxf(sPrev, FLT_MIN_NORM);
    float outv = __log2f(sP) * LN2F + S;
    if ((lane & 31) == 0) out[outbase + CL - 1] = outv;
  }
}

// ---------------- K4a: per-subject prefix of chunk offsets
__global__ void k_stitch(const float* __restrict__ out, const float* __restrict__ Mcc,
                         float* __restrict__ Delta)
{
  const int b = blockIdx.x;
  const int c = threadIdx.x;     // 64 threads
  float term = 0.0f;
  if (c > 0) term = out[b * TT + (c << 6) - 1] - Mcc[(b << 6) + c];
  for (int off = 1; off < 64; off <<= 1) {
    float up = __shfl_up(term, off);
    if (c >= off) term += up;
  }
  Delta[(b << 6) + c] = term;
}

// ---------------- K4b: add offsets
__global__ void k_add(float* __restrict__ out, const float* __restrict__ Delta)
{
  const int i = blockIdx.x * 256 + threadIdx.x;   // i < B*T
  const int b = i >> 12;
  const int t = i & 4095;
  out[i] += Delta[(b << 6) + (t >> 6)];
}

extern "C" void kernel_launch(void* const* d_in, const int* in_sizes, int n_in,
                              void* d_out, int out_size, void* d_ws, size_t ws_size,
                              hipStream_t stream) {
  const float* X   = (const float*)d_in[0];
  const float* tm  = (const float*)d_in[1];
  const float* sp  = (const float*)d_in[2];
  const float* mus = (const float*)d_in[3];
  const float* lv  = (const float*)d_in[4];
  float* out = (float*)d_out;

  char* ws = (char*)d_ws;
  size_t off = 0;
  uint32_t* blin32 = (uint32_t*)(ws + off); off += (size_t)BB * TT * NS * 2 + 4096;
  float* Kcv   = (float*)(ws + off); off += (size_t)BB * CH * 4;
  float* Mcc   = (float*)(ws + off); off += (size_t)BB * CH * 4;
  float* Delta = (float*)(ws + off); off += (size_t)BB * CH * 4;
  float* Amat  = (float*)(ws + off); off += (size_t)NS * NS * 4;
  float* pivec = (float*)(ws + off); off += 256;
  float* UT    = (float*)(ws + off); off += (size_t)NS * DD * 4;
  float* VT    = (float*)(ws + off); off += (size_t)NS * DD * 4;
  float* bias  = (float*)(ws + off); off += 256;

  k_pre<<<dim3(1), dim3(1024), 0, stream>>>(tm, sp, mus, lv, Amat, pivec, UT, VT, bias);
  k_emis<<<dim3(BB * CH / 2), dim3(256), 0, stream>>>(X, UT, VT, bias, blin32, Kcv);
  k_scan<<<dim3(512), dim3(256), 0, stream>>>(blin32, Kcv, Amat, pivec, out, Mcc);
  k_stitch<<<dim3(BB), dim3(64), 0, stream>>>(out, Mcc, Delta);
  k_add<<<dim3((BB * TT) / 256), dim3(256), 0, stream>>>(out, Delta);
}